// Round 7
// baseline (1107.858 us; speedup 1.0000x reference)
//
#include <hip/hip_runtime.h>

#define NPIX (8 * 1024 * 1024)
#define IN 8
#define HID 16
#define OUTC 3
#define BLK 256
#define PPT 2   // pixels per thread

// f16x2 pair type for v_dot2_f32_f16 (fdot2 accepts _Float16 vectors;
// cvt_pkrtz returns __fp16 vectors -> bit_cast between them, both 4 B).
typedef _Float16 f16x2 __attribute__((ext_vector_type(2)));

__device__ __forceinline__ f16x2 pkrtz(float lo, float hi) {
    return __builtin_bit_cast(f16x2, __builtin_amdgcn_cvt_pkrtz(lo, hi));
}

// d_ws layout (u32-indexed):
// [0] mask-format flag; weights transposed + packed as f16x2 pairs so each
// output-neuron row is 16B-aligned and contiguous.
#define WS_W0H 16    // 16 rows x 4 u32   (w0^T, f16 pairs over IN)
#define WS_W1H 80    // 16 rows x 8 u32   (w1^T, f16 pairs over HID)
#define WS_W2H 208   //  3 rows x 8 u32   (w2^T)
#define WS_B0  240   // f32 x16
#define WS_B1  256   // f32 x16
#define WS_B2  272   // f32 x3
#define WS_N   276   // total u32 copied to LDS

__device__ __forceinline__ unsigned int pack2(float lo, float hi) {
    _Float16 a = (_Float16)lo, b = (_Float16)hi;
    unsigned short ua = __builtin_bit_cast(unsigned short, a);
    unsigned short ub = __builtin_bit_cast(unsigned short, b);
    return (unsigned int)ua | ((unsigned int)ub << 16);
}

__global__ void prep_kernel(const unsigned int* __restrict__ m,
                            const float* __restrict__ w0, const float* __restrict__ b0,
                            const float* __restrict__ w1, const float* __restrict__ b1,
                            const float* __restrict__ w2, const float* __restrict__ b2,
                            float* __restrict__ ws) {
    const int t = threadIdx.x;  // 256
    unsigned int* wsu = (unsigned int*)ws;
    if (t < 64) {  // mask format detect: packed bool bytes give u32 words > 1 a.s.
        unsigned int acc = 0u;
        #pragma unroll
        for (int k = 0; k < 8; ++k) acc |= m[t * 8 + k];
        const unsigned long long big = __ballot(acc > 1u);
        if (t == 0) ((int*)ws)[0] = big ? 1 : 0;   // 1 => byte-mask
    }
    if (t < 64)  { int j = t >> 2, k = t & 3;
        wsu[WS_W0H + j * 4 + k] = pack2(w0[(2 * k) * HID + j], w0[(2 * k + 1) * HID + j]); }
    if (t < 128) { int j = t >> 3, k = t & 7;
        wsu[WS_W1H + j * 8 + k] = pack2(w1[(2 * k) * HID + j], w1[(2 * k + 1) * HID + j]); }
    if (t < 24)  { int j = t >> 3, k = t & 7;
        wsu[WS_W2H + j * 8 + k] = pack2(w2[(2 * k) * OUTC + j], w2[(2 * k + 1) * OUTC + j]); }
    if (t < HID)  { ws[WS_B0 + t] = b0[t]; ws[WS_B1 + t] = b1[t]; }
    if (t < OUTC) { ws[WS_B2 + t] = b2[t]; }
}

// Round-7 theory: weights (276 u32) exceed the SGPR file, so the allocator
// materializes each per-use from the AGPR side of the unified file ->
// ~1400 extra VALU instrs/thread (round-6 PMC: 2036 VALU/thread vs ~600 in
// source, VALUBusy 87%). Fix: weights in LDS. ds_read issues on the LGKM
// pipe (not the VALU port), same-address access broadcasts conflict-free,
// and the fdot2 stream keeps the VALU port fed from other waves.
__global__ void __launch_bounds__(BLK, 4) colormlp_kernel(
    const float* __restrict__ x,
    const void*  __restrict__ mask,
    const float* __restrict__ ws,
    float* __restrict__ out)
{
    __shared__ __align__(16) unsigned int sW[WS_N];
    __shared__ __align__(16) float sOut[BLK * PPT * OUTC];

    const int t = threadIdx.x;
    const int mflag = ((const int*)ws)[0];   // uniform scalar load, pre-barrier

    // ---- stage weights+biases into LDS (276 u32 = 1104 B) ----
    {
        const unsigned int* wsu = (const unsigned int*)ws;
        if (t < 256)        sW[t] = wsu[t];
        if (t < WS_N - 256) sW[256 + t] = wsu[256 + t];
    }

    const unsigned int pix0 = (blockIdx.x * BLK + t) * PPT;

    // ---- load x: 2 consecutive pixels x 8 ch = 64 B contiguous per lane ----
    float4 x0[PPT], x1[PPT];
    {
        const float4* xp = (const float4*)(x + (size_t)pix0 * IN);
        #pragma unroll
        for (int p = 0; p < PPT; ++p) { x0[p] = xp[2 * p]; x1[p] = xp[2 * p + 1]; }
    }

    __syncthreads();   // weights visible

    // ---- pack x to f16 pairs (v_cvt_pkrtz, 4/pixel) ----
    f16x2 xh[PPT][4];
    #pragma unroll
    for (int p = 0; p < PPT; ++p) {
        xh[p][0] = pkrtz(x0[p].x, x0[p].y);
        xh[p][1] = pkrtz(x0[p].z, x0[p].w);
        xh[p][2] = pkrtz(x1[p].x, x1[p].y);
        xh[p][3] = pkrtz(x1[p].z, x1[p].w);
    }

    // ---- layer 0: h0 = relu(x @ w0 + b0); w0 row = 1x ds_read_b128 ----
    f16x2 h0h[PPT][HID / 2];
    {
        float h0[PPT][HID];
        #pragma unroll
        for (int j = 0; j < HID; ++j) {
            const uint4 wr = *(const uint4*)&sW[WS_W0H + j * 4];
            f16x2 w[4] = { __builtin_bit_cast(f16x2, wr.x), __builtin_bit_cast(f16x2, wr.y),
                           __builtin_bit_cast(f16x2, wr.z), __builtin_bit_cast(f16x2, wr.w) };
            const float bj = __builtin_bit_cast(float, sW[WS_B0 + j]);
            #pragma unroll
            for (int p = 0; p < PPT; ++p) {
                float acc = bj;
                #pragma unroll
                for (int k = 0; k < 4; ++k) acc = __builtin_amdgcn_fdot2(xh[p][k], w[k], acc, false);
                h0[p][j] = fmaxf(acc, 0.0f);
            }
        }
        #pragma unroll
        for (int p = 0; p < PPT; ++p)
            #pragma unroll
            for (int i = 0; i < HID / 2; ++i)
                h0h[p][i] = pkrtz(h0[p][2 * i], h0[p][2 * i + 1]);
    }

    // ---- layer 1: h1 = relu(h0 @ w1 + b1); w1 row = 2x ds_read_b128 ----
    f16x2 h1h[PPT][HID / 2];
    {
        float h1[PPT][HID];
        #pragma unroll
        for (int j = 0; j < HID; ++j) {
            const uint4 wa = *(const uint4*)&sW[WS_W1H + j * 8];
            const uint4 wb = *(const uint4*)&sW[WS_W1H + j * 8 + 4];
            f16x2 w[8] = { __builtin_bit_cast(f16x2, wa.x), __builtin_bit_cast(f16x2, wa.y),
                           __builtin_bit_cast(f16x2, wa.z), __builtin_bit_cast(f16x2, wa.w),
                           __builtin_bit_cast(f16x2, wb.x), __builtin_bit_cast(f16x2, wb.y),
                           __builtin_bit_cast(f16x2, wb.z), __builtin_bit_cast(f16x2, wb.w) };
            const float bj = __builtin_bit_cast(float, sW[WS_B1 + j]);
            #pragma unroll
            for (int p = 0; p < PPT; ++p) {
                float acc = bj;
                #pragma unroll
                for (int k = 0; k < 8; ++k) acc = __builtin_amdgcn_fdot2(h0h[p][k], w[k], acc, false);
                h1[p][j] = fmaxf(acc, 0.0f);
            }
        }
        #pragma unroll
        for (int p = 0; p < PPT; ++p)
            #pragma unroll
            for (int i = 0; i < HID / 2; ++i)
                h1h[p][i] = pkrtz(h1[p][2 * i], h1[p][2 * i + 1]);
    }

    // ---- mask load (uniform branch on detected layout) ----
    int mv[PPT];
    if (mflag) {
        uchar2 m2 = *(const uchar2*)((const unsigned char*)mask + pix0);
        mv[0] = m2.x; mv[1] = m2.y;
    } else {
        int2 m2 = *(const int2*)((const int*)mask + pix0);
        mv[0] = m2.x; mv[1] = m2.y;
    }

    // ---- layer 2 + sigmoid + blend (blend kept in exact f32) ----
    #pragma unroll
    for (int p = 0; p < PPT; ++p) {
        const float res = x0[p].w;
        float ov[OUTC];
        #pragma unroll
        for (int j = 0; j < OUTC; ++j) {
            const uint4 wa = *(const uint4*)&sW[WS_W2H + j * 8];
            const uint4 wb = *(const uint4*)&sW[WS_W2H + j * 8 + 4];
            f16x2 w[8] = { __builtin_bit_cast(f16x2, wa.x), __builtin_bit_cast(f16x2, wa.y),
                           __builtin_bit_cast(f16x2, wa.z), __builtin_bit_cast(f16x2, wa.w),
                           __builtin_bit_cast(f16x2, wb.x), __builtin_bit_cast(f16x2, wb.y),
                           __builtin_bit_cast(f16x2, wb.z), __builtin_bit_cast(f16x2, wb.w) };
            float acc = __builtin_bit_cast(float, sW[WS_B2 + j]);
            #pragma unroll
            for (int k = 0; k < 8; ++k)
                acc = __builtin_amdgcn_fdot2(h1h[p][k], w[k], acc, false);
            float e = __expf(-acc);
            float y = __builtin_amdgcn_rcpf(1.0f + e);
            float rgb = (j == 0) ? x0[p].x : (j == 1) ? x0[p].y : x0[p].z;
            float bl = fmaf(res, y - rgb, rgb);      // (1-res)*rgb + res*y
            ov[j] = mv[p] ? bl : 0.0f;
        }
        float* sp = sOut + (size_t)(t * PPT + p) * OUTC;
        ((float2*)sp)[0] = make_float2(ov[0], ov[1]);
        sp[2] = ov[2];
    }
    __syncthreads();

    // ---- contiguous wave-level stores: 384 float4 = 6 KB per block ----
    {
        const float4* s4 = (const float4*)sOut;
        float4* o4 = (float4*)(out + (size_t)blockIdx.x * (BLK * PPT * OUTC));
        o4[t] = s4[t];
        if (t < (BLK * PPT * OUTC) / 4 - BLK) o4[BLK + t] = s4[BLK + t];
    }
}

extern "C" void kernel_launch(void* const* d_in, const int* in_sizes, int n_in,
                              void* d_out, int out_size, void* d_ws, size_t ws_size,
                              hipStream_t stream) {
    const float* x    = (const float*)d_in[0];
    const void*  mask = d_in[1];
    const float* w0   = (const float*)d_in[2];
    const float* b0   = (const float*)d_in[3];
    const float* w1   = (const float*)d_in[4];
    const float* b1   = (const float*)d_in[5];
    const float* w2   = (const float*)d_in[6];
    const float* b2   = (const float*)d_in[7];
    float* out = (float*)d_out;
    float* ws  = (float*)d_ws;

    prep_kernel<<<1, BLK, 0, stream>>>((const unsigned int*)mask,
                                       w0, b0, w1, b1, w2, b2, ws);

    const int grid = NPIX / (BLK * PPT);  // 16384
    colormlp_kernel<<<grid, BLK, 0, stream>>>(x, mask, ws, out);
}

// Round 8
// 436.034 us; speedup vs baseline: 2.5408x; 2.5408x over previous
//
#include <hip/hip_runtime.h>

#define NPIX (8 * 1024 * 1024)
#define IN 8
#define HID 16
#define OUTC 3
#define BLK 256
#define CHAINS 8              // 16-px MFMA chains per wave
#define PXB (4 * CHAINS * 16) // pixels per block = 512
// grid = NPIX / PXB = 16384 blocks

typedef __fp16 f16x2 __attribute__((ext_vector_type(2)));
typedef __fp16 f16x4 __attribute__((ext_vector_type(4)));
typedef float  f32x4 __attribute__((ext_vector_type(4)));

__device__ __forceinline__ f16x4 mk4(float a, float b, float c, float d) {
    f16x2 p0 = __builtin_amdgcn_cvt_pkrtz(a, b);
    f16x2 p1 = __builtin_amdgcn_cvt_pkrtz(c, d);
    uint2 u = make_uint2(__builtin_bit_cast(unsigned int, p0),
                         __builtin_bit_cast(unsigned int, p1));
    return __builtin_bit_cast(f16x4, u);
}

// d_ws layout (u32-indexed). A-fragments are stored PER LANE so the kernel
// prologue is one 8B load per layer: lane l, reg-half i holds
// W[k=(l>>4)*4+i][m=l&15]  (A operand of mfma_16x16x16_f16, M=neurons, K=in).
#define WS_A0 16     // 128 u32: w0 (k>=8 zero-padded)
#define WS_A1 144    // 128 u32: w1
#define WS_A2 272    // 128 u32: w2 (cols m>=3 zero)
#define WS_B0 400    // f32 x16
#define WS_B1 416    // f32 x16
#define WS_B2 432    // f32 x16 (3 real + zero pad)

__device__ __forceinline__ unsigned int pack2(float lo, float hi) {
    __fp16 a = (__fp16)lo, b = (__fp16)hi;
    unsigned short ua = __builtin_bit_cast(unsigned short, a);
    unsigned short ub = __builtin_bit_cast(unsigned short, b);
    return (unsigned int)ua | ((unsigned int)ub << 16);
}

__global__ void prep_kernel(const unsigned int* __restrict__ m,
                            const float* __restrict__ w0, const float* __restrict__ b0,
                            const float* __restrict__ w1, const float* __restrict__ b1,
                            const float* __restrict__ w2, const float* __restrict__ b2,
                            float* __restrict__ ws) {
    const int t = threadIdx.x;  // 256
    unsigned int* wsu = (unsigned int*)ws;
    if (t < 64) {  // mask format detect: packed bool bytes give u32 words > 1 a.s.
        unsigned int acc = 0u;
        #pragma unroll
        for (int k = 0; k < 8; ++k) acc |= m[t * 8 + k];
        const unsigned long long big = __ballot(acc > 1u);
        if (t == 0) ((int*)ws)[0] = big ? 1 : 0;   // 1 => byte-mask
    }
    if (t < 128) {             // t = 2*lane + j ; pair j covers k0+2j, k0+2j+1
        const int l = t >> 1, j = t & 1;
        const int mcol = l & 15;
        const int k0 = ((l >> 4) << 2) + 2 * j;
        const float a0lo = (k0     < IN) ? w0[(k0    ) * HID + mcol] : 0.0f;
        const float a0hi = (k0 + 1 < IN) ? w0[(k0 + 1) * HID + mcol] : 0.0f;
        wsu[WS_A0 + t] = pack2(a0lo, a0hi);
        wsu[WS_A1 + t] = pack2(w1[k0 * HID + mcol], w1[(k0 + 1) * HID + mcol]);
        wsu[WS_A2 + t] = (mcol < OUTC)
                       ? pack2(w2[k0 * OUTC + mcol], w2[(k0 + 1) * OUTC + mcol]) : 0u;
    }
    if (t < 16) {
        ws[WS_B0 + t] = b0[t];
        ws[WS_B1 + t] = b1[t];
        ws[WS_B2 + t] = (t < OUTC) ? b2[t] : 0.0f;
    }
}

// Round-8: MFMA chain. D = A*B + C with A = W^T (M=16 neurons, K=16 in),
// B = X^T (K=16 in, N=16 pixels), C = bias broadcast. Key property: the D
// fragment layout [row=(l>>4)*4+i, col=l&15] IS the next layer's B layout
// [k=(l>>4)*4+i, col=l&15] -> layers chain in-register with no shuffles.
// Weights: 2 VGPR per layer, loaded once. The 432 MACs/px leave the VALU
// port entirely (round-6 PMC: VALUBusy 87%, MfmaUtil 0 -> issue-bound).
__global__ void __launch_bounds__(BLK, 4) colormlp_kernel(
    const float* __restrict__ x,
    const void*  __restrict__ mask,
    const float* __restrict__ ws,
    float* __restrict__ out)
{
    __shared__ __align__(16) float sOut[PXB * OUTC];   // 6 KB

    const int t = threadIdx.x;
    const int w = t >> 6;          // wave 0..3
    const int l = t & 63;          // lane
    const unsigned int* wsu = (const unsigned int*)ws;
    const int mflag = ((const int*)ws)[0];

    // ---- per-lane weight fragments: one 8B load per layer ----
    const f16x4 a0 = __builtin_bit_cast(f16x4, *(const uint2*)&wsu[WS_A0 + 2 * l]);
    const f16x4 a1 = __builtin_bit_cast(f16x4, *(const uint2*)&wsu[WS_A1 + 2 * l]);
    const f16x4 a2 = __builtin_bit_cast(f16x4, *(const uint2*)&wsu[WS_A2 + 2 * l]);

    // ---- bias C fragments: rows (l>>4)*4+i, broadcast over cols ----
    const int g4 = (l >> 4) << 2;
    const f32x4 cb0 = *(const f32x4*)&ws[WS_B0 + g4];
    const f32x4 cb1 = *(const f32x4*)&ws[WS_B1 + g4];
    const f32x4 cb2 = *(const f32x4*)&ws[WS_B2 + g4];

    const unsigned int wavebase = (blockIdx.x * 4 + w) * (CHAINS * 16);

    #pragma unroll 2
    for (int c = 0; c < CHAINS; ++c) {
        const unsigned int px = wavebase + c * 16 + (l & 15);

        // B0: lanes g0/g1 carry channels 0-3 / 4-7 of pixel l&15; g2/g3 zero
        // (A0 rows k>=8 are zero too). Lanes 0-15 keep xv = (r,g,b,res).
        float4 xv = make_float4(0.f, 0.f, 0.f, 0.f);
        if (l < 32) xv = ((const float4*)x)[(size_t)px * 2 + (l >> 4)];

        f16x4 bf = mk4(xv.x, xv.y, xv.z, xv.w);
        f32x4 d = __builtin_amdgcn_mfma_f32_16x16x16f16(a0, bf, cb0, 0, 0, 0);
        bf = mk4(fmaxf(d[0], 0.f), fmaxf(d[1], 0.f), fmaxf(d[2], 0.f), fmaxf(d[3], 0.f));
        d = __builtin_amdgcn_mfma_f32_16x16x16f16(a1, bf, cb1, 0, 0, 0);
        bf = mk4(fmaxf(d[0], 0.f), fmaxf(d[1], 0.f), fmaxf(d[2], 0.f), fmaxf(d[3], 0.f));
        d = __builtin_amdgcn_mfma_f32_16x16x16f16(a2, bf, cb2, 0, 0, 0);

        // epilogue: lanes 0-15 hold out-neurons 0-2 (regs 0-2) of pixel l&15,
        // and xv = x0 = (rgb, res) of that same pixel.
        if (l < 16) {
            const int mv = mflag ? (int)((const unsigned char*)mask)[px]
                                 : ((const int*)mask)[px];
            const float res = xv.w;
            float ov[OUTC];
            #pragma unroll
            for (int i = 0; i < OUTC; ++i) {
                const float e = __expf(-d[i]);
                const float y = __builtin_amdgcn_rcpf(1.0f + e);
                const float rgb = (i == 0) ? xv.x : (i == 1) ? xv.y : xv.z;
                const float bl = fmaf(res, y - rgb, rgb);   // (1-res)*rgb + res*y
                ov[i] = mv ? bl : 0.0f;
            }
            float* sp = sOut + (size_t)((w * CHAINS + c) * 16 + (l & 15)) * OUTC;
            ((float2*)sp)[0] = make_float2(ov[0], ov[1]);
            sp[2] = ov[2];
        }
    }
    __syncthreads();

    // ---- contiguous block store: 384 float4 = 6 KB ----
    {
        const float4* s4 = (const float4*)sOut;
        float4* o4 = (float4*)(out + (size_t)blockIdx.x * (PXB * OUTC));
        o4[t] = s4[t];
        if (t < (PXB * OUTC) / 4 - BLK) o4[BLK + t] = s4[BLK + t];
    }
}

extern "C" void kernel_launch(void* const* d_in, const int* in_sizes, int n_in,
                              void* d_out, int out_size, void* d_ws, size_t ws_size,
                              hipStream_t stream) {
    const float* x    = (const float*)d_in[0];
    const void*  mask = d_in[1];
    const float* w0   = (const float*)d_in[2];
    const float* b0   = (const float*)d_in[3];
    const float* w1   = (const float*)d_in[4];
    const float* b1   = (const float*)d_in[5];
    const float* w2   = (const float*)d_in[6];
    const float* b2   = (const float*)d_in[7];
    float* out = (float*)d_out;
    float* ws  = (float*)d_ws;

    prep_kernel<<<1, BLK, 0, stream>>>((const unsigned int*)mask,
                                       w0, b0, w1, b1, w2, b2, ws);

    const int grid = NPIX / PXB;  // 16384
    colormlp_kernel<<<grid, BLK, 0, stream>>>(x, mask, ws, out);
}